// Round 1
// baseline (783.245 us; speedup 1.0000x reference)
//
#include <hip/hip_runtime.h>
#include <hip/hip_bf16.h>
#include <cstdint>

// MinGRU: g=sigmoid(xWg^T+bg), c=tanh(xWh^T+bh), h_t = g*h_{t-1} + (1-g)*c
// B=8, L=4096, D=1024.  M = B*L = 32768, K = E = 1024.
//
// Strategy:
//  - split-bf16 GEMM on MFMA (x=hi+lo, W=hi+lo, 3 products -> ~fp32 accuracy)
//  - W pre-split into ws (bf16 hi/lo), staged via global_load_lds width=16
//  - x converted fp32->hi/lo bf16 in-register during staging (padded LDS)
//  - chunked parallel scan over L (Lc=64, C=64 chunks)
// ws layout (bytes): [0..2M) Wg_hi | [2M..4M) Wg_lo | [4M..6M) Wh_hi |
//   [6M..8M) Wh_lo | [8M..8M+134M) c array fp32 | Ac 2M | Bc 2M | Hst 2M
// total ~149 MB required.

using u16   = unsigned short;
using f32x4 = __attribute__((ext_vector_type(4))) float;
using s16x8 = __attribute__((ext_vector_type(8))) short;
using u16x4 = __attribute__((ext_vector_type(4))) u16;

#define M_TOTAL 32768
#define K_DIM   1024
#define E_DIM   1024
#define LCH     64     // scan chunk length
#define NCH     64     // chunks per sequence (4096/64)

__device__ inline u16 bf16_rtne(float f) {
    uint32_t u = __float_as_uint(f);
    u += 0x7FFFu + ((u >> 16) & 1u);
    return (u16)(u >> 16);
}

// ---------------- W pre-split: fp32 -> bf16 hi (RTNE) + bf16 lo ----------------
__global__ void split_w(const float* __restrict__ w, u16* __restrict__ hi,
                        u16* __restrict__ lo, int n4) {
    int i = blockIdx.x * blockDim.x + threadIdx.x;
    if (i >= n4) return;
    f32x4 f = ((const f32x4*)w)[i];
    u16x4 h, l;
#pragma unroll
    for (int c = 0; c < 4; ++c) {
        float fv = f[c];
        u16 hv = bf16_rtne(fv);
        h[c] = hv;
        float fh = __uint_as_float(((uint32_t)hv) << 16);
        l[c] = bf16_rtne(fv - fh);
    }
    ((u16x4*)hi)[i] = h;
    ((u16x4*)lo)[i] = l;
}

// ---------------- GEMM + activation ----------------
// grid: (M/128, E/128, 2). z=0 -> sigmoid(x Wg^T + bg) -> out_a (d_out)
//                          z=1 -> tanh(x Wh^T + bh)    -> out_c (ws)
__global__ __launch_bounds__(256, 2) void gemm_act(
    const float* __restrict__ x,
    const u16* __restrict__ wg_hi, const u16* __restrict__ wg_lo,
    const u16* __restrict__ wh_hi, const u16* __restrict__ wh_lo,
    const float* __restrict__ bg, const float* __restrict__ bh,
    float* __restrict__ out_a, float* __restrict__ out_c) {

    const int which = blockIdx.z;
    const u16* __restrict__ Whi = which ? wh_hi : wg_hi;
    const u16* __restrict__ Wlo = which ? wh_lo : wg_lo;
    const float* __restrict__ bias = which ? bh : bg;
    float* __restrict__ out = which ? out_c : out_a;

    const int m0 = blockIdx.x * 128;
    const int e0 = blockIdx.y * 128;

    // A padded to stride 40 (80B: 16B-aligned frags, 2-way bank alias = free)
    __shared__ __align__(16) u16 lsAh[128 * 40];
    __shared__ __align__(16) u16 lsAl[128 * 40];
    // B unpadded stride 32 (global_load_lds needs contiguous lane order)
    __shared__ __align__(16) u16 lsBh[128 * 32];
    __shared__ __align__(16) u16 lsBl[128 * 32];

    const int tid  = threadIdx.x;
    const int lane = tid & 63;
    const int wave = tid >> 6;
    const int wr = wave >> 1, wc = wave & 1;  // 2x2 wave grid, each 64x64
    const int lr = lane & 15;                 // row/col within 16
    const int kg = lane >> 4;                 // k-group (quad)

    f32x4 acc[4][4];
#pragma unroll
    for (int tr = 0; tr < 4; ++tr)
#pragma unroll
        for (int tc = 0; tc < 4; ++tc)
            acc[tr][tc] = (f32x4){0.f, 0.f, 0.f, 0.f};

    for (int kt = 0; kt < K_DIM / 32; ++kt) {
        __syncthreads();  // previous iter's LDS reads done before overwrite

        // ---- stage B (W rows) via async global->LDS, 16B chunks ----
#pragma unroll
        for (int j = 0; j < 2; ++j) {
            int ch  = tid + 256 * j;          // 512 chunks of 16B = 8KB
            int row = ch >> 2;                // e-row 0..127
            int kq  = ch & 3;                 // 8-elem k group
            size_t goff = (size_t)(e0 + row) * K_DIM + kt * 32 + kq * 8;
            __builtin_amdgcn_global_load_lds(
                (const __attribute__((address_space(1))) void*)(Whi + goff),
                (__attribute__((address_space(3))) void*)(&lsBh[ch * 8]), 16, 0, 0);
            __builtin_amdgcn_global_load_lds(
                (const __attribute__((address_space(1))) void*)(Wlo + goff),
                (__attribute__((address_space(3))) void*)(&lsBl[ch * 8]), 16, 0, 0);
        }

        // ---- stage A (x rows), convert fp32 -> hi/lo bf16 ----
#pragma unroll
        for (int j = 0; j < 4; ++j) {
            int q   = tid + 256 * j;          // 1024 float4s = 128x32 fp32
            int row = q >> 3;                 // m-row 0..127
            int kq  = q & 7;                  // float4 within row
            f32x4 f = *(const f32x4*)(x + (size_t)(m0 + row) * K_DIM + kt * 32 + kq * 4);
            u16x4 h, l;
#pragma unroll
            for (int c = 0; c < 4; ++c) {
                uint32_t u = __float_as_uint(f[c]);
                h[c] = (u16)(u >> 16);        // truncation split
                float r = f[c] - __uint_as_float(u & 0xFFFF0000u);
                l[c] = bf16_rtne(r);
            }
            *(u16x4*)&lsAh[row * 40 + kq * 4] = h;
            *(u16x4*)&lsAl[row * 40 + kq * 4] = l;
        }

        __syncthreads();

        // ---- fragments + MFMA ----
        s16x8 ah[4], al[4];
#pragma unroll
        for (int tr = 0; tr < 4; ++tr) {
            int r = wr * 64 + tr * 16 + lr;
            ah[tr] = *(const s16x8*)&lsAh[r * 40 + kg * 8];
            al[tr] = *(const s16x8*)&lsAl[r * 40 + kg * 8];
        }
#pragma unroll
        for (int tc = 0; tc < 4; ++tc) {
            int e = wc * 64 + tc * 16 + lr;
            s16x8 bh8 = *(const s16x8*)&lsBh[e * 32 + kg * 8];
            s16x8 bl8 = *(const s16x8*)&lsBl[e * 32 + kg * 8];
#pragma unroll
            for (int tr = 0; tr < 4; ++tr) {
                acc[tr][tc] = __builtin_amdgcn_mfma_f32_16x16x32_bf16(ah[tr], bh8, acc[tr][tc], 0, 0, 0);
                acc[tr][tc] = __builtin_amdgcn_mfma_f32_16x16x32_bf16(ah[tr], bl8, acc[tr][tc], 0, 0, 0);
                acc[tr][tc] = __builtin_amdgcn_mfma_f32_16x16x32_bf16(al[tr], bh8, acc[tr][tc], 0, 0, 0);
            }
        }
    }

    // ---- epilogue: bias + activation, write fp32 ----
#pragma unroll
    for (int tc = 0; tc < 4; ++tc) {
        int e = e0 + wc * 64 + tc * 16 + lr;
        float bv = bias[e];
#pragma unroll
        for (int tr = 0; tr < 4; ++tr) {
            int mb = m0 + wr * 64 + tr * 16 + kg * 4;
#pragma unroll
            for (int i = 0; i < 4; ++i) {
                float z = acc[tr][tc][i] + bv;
                float v = which ? tanhf(z) : 1.f / (1.f + __expf(-z));
                out[(size_t)(mb + i) * E_DIM + e] = v;
            }
        }
    }
}

// ---------------- scan pass 1: per-chunk affine composite ----------------
__global__ void chunk_compose(const float* __restrict__ a_arr,
                              const float* __restrict__ c_arr,
                              float* __restrict__ Ac, float* __restrict__ Bc) {
    int d  = threadIdx.x;   // 0..1023
    int ch = blockIdx.x;    // 0..63
    int b  = blockIdx.y;    // 0..7
    size_t base = ((size_t)b * 4096 + (size_t)ch * LCH) * 1024 + d;
    float A = 1.f, Bv = 0.f;
#pragma unroll 4
    for (int t = 0; t < LCH; ++t) {
        size_t idx = base + (size_t)t * 1024;
        float g = a_arr[idx];
        float c = c_arr[idx];
        float bb = (1.f - g) * c;
        A  = g * A;
        Bv = g * Bv + bb;
    }
    size_t o = ((size_t)b * NCH + ch) * 1024 + d;
    Ac[o] = A;
    Bc[o] = Bv;
}

// ---------------- scan pass 2: prefix over chunks -> h at chunk entry ----------------
__global__ void chunk_prefix(const float* __restrict__ Ac, const float* __restrict__ Bc,
                             const float* __restrict__ hidden, float* __restrict__ Hst) {
    int d = threadIdx.x;
    int b = blockIdx.x;
    float h = hidden[b * 1024 + d];
    for (int ch = 0; ch < NCH; ++ch) {
        size_t o = ((size_t)b * NCH + ch) * 1024 + d;
        float A = Ac[o], Bv = Bc[o];
        Hst[o] = h;
        h = A * h + Bv;
    }
}

// ---------------- scan pass 3: apply (in-place over a in d_out) ----------------
__global__ void chunk_apply(const float* __restrict__ c_arr,
                            const float* __restrict__ Hst,
                            float* __restrict__ out) {
    int d  = threadIdx.x;
    int ch = blockIdx.x;
    int b  = blockIdx.y;
    size_t base = ((size_t)b * 4096 + (size_t)ch * LCH) * 1024 + d;
    float h = Hst[((size_t)b * NCH + ch) * 1024 + d];
#pragma unroll 4
    for (int t = 0; t < LCH; ++t) {
        size_t idx = base + (size_t)t * 1024;
        float g = out[idx];     // a value (read before overwrite, same thread)
        float c = c_arr[idx];
        h = g * h + (1.f - g) * c;
        out[idx] = h;
    }
}

extern "C" void kernel_launch(void* const* d_in, const int* in_sizes, int n_in,
                              void* d_out, int out_size, void* d_ws, size_t ws_size,
                              hipStream_t stream) {
    const float* x      = (const float*)d_in[0];
    const float* hidden = (const float*)d_in[1];
    const float* Wg     = (const float*)d_in[2];
    const float* bg     = (const float*)d_in[3];
    const float* Wh     = (const float*)d_in[4];
    const float* bh     = (const float*)d_in[5];
    float* out = (float*)d_out;

    char* ws = (char*)d_ws;
    const size_t WSEG = 2u * 1024u * 1024u;            // 2MB per W half
    u16* wg_hi = (u16*)(ws + 0 * WSEG);
    u16* wg_lo = (u16*)(ws + 1 * WSEG);
    u16* wh_hi = (u16*)(ws + 2 * WSEG);
    u16* wh_lo = (u16*)(ws + 3 * WSEG);
    float* c_arr = (float*)(ws + 4 * WSEG);
    const size_t CBYTES = (size_t)M_TOTAL * E_DIM * 4; // 134 MB
    float* Ac  = (float*)(ws + 4 * WSEG + CBYTES);
    float* Bc  = (float*)(ws + 4 * WSEG + CBYTES + WSEG);
    float* Hst = (float*)(ws + 4 * WSEG + CBYTES + 2 * WSEG);

    // 1) split weights into bf16 hi/lo
    split_w<<<dim3(1024), 256, 0, stream>>>(Wg, wg_hi, wg_lo, (1024 * 1024) / 4);
    split_w<<<dim3(1024), 256, 0, stream>>>(Wh, wh_hi, wh_lo, (1024 * 1024) / 4);

    // 2) fused GEMM + activation (z=0: gate->d_out, z=1: cand->ws)
    gemm_act<<<dim3(M_TOTAL / 128, E_DIM / 128, 2), 256, 0, stream>>>(
        x, wg_hi, wg_lo, wh_hi, wh_lo, bg, bh, out, c_arr);

    // 3) chunked scan
    chunk_compose<<<dim3(NCH, 8), 1024, 0, stream>>>(out, c_arr, Ac, Bc);
    chunk_prefix<<<dim3(8), 1024, 0, stream>>>(Ac, Bc, hidden, Hst);
    chunk_apply<<<dim3(NCH, 8), 1024, 0, stream>>>(c_arr, Hst, out);
}

// Round 2
// 698.711 us; speedup vs baseline: 1.1210x; 1.1210x over previous
//
#include <hip/hip_runtime.h>
#include <hip/hip_bf16.h>
#include <cstdint>

// MinGRU: g=sigmoid(xWg^T+bg), c=tanh(xWh^T+bh), h_t = g*h_{t-1} + (1-g)*c
// B=8, L=4096, D=1024.  M = B*L = 32768, K = E = 1024.
//
// R2 structure:
//  - split-bf16 GEMM on MFMA (x=hi+lo, W=hi+lo, 3 products -> ~fp32 accuracy)
//  - z-merged: one block computes BOTH g and c tiles (x staged once for both)
//  - W pre-split into ws (bf16 hi/lo), staged via global_load_lds width=16
//  - g,c stored as fp16 (halves intermediate traffic; err 2^-11 << budget)
//  - chunked parallel scan over L (Lc=64, C=64 chunks), half8 vectorized
// ws layout (bytes): 4 x 2M W splits | g fp16 64MiB | c fp16 64MiB |
//   Ac 2M | Bc 2M | Hst 2M   -> ~142 MiB total.

using u16   = unsigned short;
using f32x4 = __attribute__((ext_vector_type(4))) float;
using s16x8 = __attribute__((ext_vector_type(8))) short;
using u16x4 = __attribute__((ext_vector_type(4))) u16;
using h16x8 = __attribute__((ext_vector_type(8))) _Float16;

#define M_TOTAL 32768
#define K_DIM   1024
#define E_DIM   1024
#define LCH     64     // scan chunk length
#define NCH     64     // chunks per sequence (4096/64)

__device__ inline u16 bf16_rtne(float f) {
    uint32_t u = __float_as_uint(f);
    u += 0x7FFFu + ((u >> 16) & 1u);
    return (u16)(u >> 16);
}

// ---------------- W pre-split: fp32 -> bf16 hi (RTNE) + bf16 lo ----------------
// grid.y = 2 selects Wg / Wh
__global__ void split_w(const float* __restrict__ wg, const float* __restrict__ wh,
                        u16* __restrict__ ws_base, int n4) {
    const float* w = blockIdx.y ? wh : wg;
    u16* hi = ws_base + (size_t)blockIdx.y * 2 * 1024 * 1024;  // elements
    u16* lo = hi + 1024 * 1024;
    int i = blockIdx.x * blockDim.x + threadIdx.x;
    if (i >= n4) return;
    f32x4 f = ((const f32x4*)w)[i];
    u16x4 h, l;
#pragma unroll
    for (int c = 0; c < 4; ++c) {
        float fv = f[c];
        u16 hv = bf16_rtne(fv);
        h[c] = hv;
        float fh = __uint_as_float(((uint32_t)hv) << 16);
        l[c] = bf16_rtne(fv - fh);
    }
    ((u16x4*)hi)[i] = h;
    ((u16x4*)lo)[i] = l;
}

__device__ inline float fast_sigmoid(float z) {
    return 1.f / (1.f + __expf(-z));
}
__device__ inline float fast_tanh(float z) {
    // tanh(z) = 1 - 2/(exp(2z)+1); saturates correctly at +/-inf
    return 1.f - 2.f / (__expf(2.f * z) + 1.f);
}

// ---------------- GEMM + activation (z-merged) ----------------
// grid: (M/128, E/128). Each block: g=sigmoid(x Wg^T+bg) -> g_out (fp16)
//                                   c=tanh   (x Wh^T+bh) -> c_out (fp16)
__global__ __launch_bounds__(256, 2) void gemm_act(
    const float* __restrict__ x,
    const u16* __restrict__ wg_hi, const u16* __restrict__ wg_lo,
    const u16* __restrict__ wh_hi, const u16* __restrict__ wh_lo,
    const float* __restrict__ bg, const float* __restrict__ bh,
    _Float16* __restrict__ g_out, _Float16* __restrict__ c_out) {

    const int m0 = blockIdx.x * 128;
    const int e0 = blockIdx.y * 128;

    // A padded to stride 40 u16 (80B rows: 16B-aligned frags, 2-way alias = free)
    __shared__ __align__(16) u16 lsAh[128 * 40];
    __shared__ __align__(16) u16 lsAl[128 * 40];
    // B unpadded stride 32 (global_load_lds needs contiguous lane order)
    // [0]=Wg_hi [1]=Wg_lo [2]=Wh_hi [3]=Wh_lo
    __shared__ __align__(16) u16 lsB[4][128 * 32];

    const int tid  = threadIdx.x;
    const int lane = tid & 63;
    const int wave = tid >> 6;
    const int wr = wave >> 1, wc = wave & 1;  // 2x2 wave grid, each 64x64
    const int lr = lane & 15;                 // row/col within 16
    const int kg = lane >> 4;                 // k-group (quad)

    const u16* __restrict__ Wptr[4] = {wg_hi, wg_lo, wh_hi, wh_lo};

    f32x4 accg[4][4], acch[4][4];
#pragma unroll
    for (int tr = 0; tr < 4; ++tr)
#pragma unroll
        for (int tc = 0; tc < 4; ++tc) {
            accg[tr][tc] = (f32x4){0.f, 0.f, 0.f, 0.f};
            acch[tr][tc] = (f32x4){0.f, 0.f, 0.f, 0.f};
        }

    for (int kt = 0; kt < K_DIM / 32; ++kt) {
        __syncthreads();  // previous iter's LDS reads done before overwrite

        // ---- stage B (4 weight regions) via async global->LDS, 16B chunks ----
#pragma unroll
        for (int rgn = 0; rgn < 4; ++rgn) {
#pragma unroll
            for (int j = 0; j < 2; ++j) {
                int ch  = tid + 256 * j;      // 512 chunks of 16B = 8KB
                int row = ch >> 2;            // e-row 0..127
                int kq  = ch & 3;             // 8-elem k group
                size_t goff = (size_t)(e0 + row) * K_DIM + kt * 32 + kq * 8;
                __builtin_amdgcn_global_load_lds(
                    (const __attribute__((address_space(1))) void*)(Wptr[rgn] + goff),
                    (__attribute__((address_space(3))) void*)(&lsB[rgn][ch * 8]), 16, 0, 0);
            }
        }

        // ---- stage A (x rows), convert fp32 -> hi/lo bf16 ----
#pragma unroll
        for (int j = 0; j < 4; ++j) {
            int q   = tid + 256 * j;          // 1024 float4s = 128x32 fp32
            int row = q >> 3;                 // m-row 0..127
            int kq  = q & 7;                  // float4 within row
            f32x4 f = *(const f32x4*)(x + (size_t)(m0 + row) * K_DIM + kt * 32 + kq * 4);
            u16x4 h, l;
#pragma unroll
            for (int c = 0; c < 4; ++c) {
                uint32_t u = __float_as_uint(f[c]);
                h[c] = (u16)(u >> 16);        // truncation split
                float r = f[c] - __uint_as_float(u & 0xFFFF0000u);
                l[c] = bf16_rtne(r);
            }
            *(u16x4*)&lsAh[row * 40 + kq * 4] = h;
            *(u16x4*)&lsAl[row * 40 + kq * 4] = l;
        }

        __syncthreads();

        // ---- fragments + MFMA (A frags shared across both GEMMs) ----
        s16x8 ah[4], al[4];
#pragma unroll
        for (int tr = 0; tr < 4; ++tr) {
            int r = wr * 64 + tr * 16 + lr;
            ah[tr] = *(const s16x8*)&lsAh[r * 40 + kg * 8];
            al[tr] = *(const s16x8*)&lsAl[r * 40 + kg * 8];
        }
#pragma unroll
        for (int tc = 0; tc < 4; ++tc) {
            int e = wc * 64 + tc * 16 + lr;
            s16x8 bgh = *(const s16x8*)&lsB[0][e * 32 + kg * 8];
            s16x8 bgl = *(const s16x8*)&lsB[1][e * 32 + kg * 8];
            s16x8 bhh = *(const s16x8*)&lsB[2][e * 32 + kg * 8];
            s16x8 bhl = *(const s16x8*)&lsB[3][e * 32 + kg * 8];
#pragma unroll
            for (int tr = 0; tr < 4; ++tr) {
                accg[tr][tc] = __builtin_amdgcn_mfma_f32_16x16x32_bf16(ah[tr], bgh, accg[tr][tc], 0, 0, 0);
                accg[tr][tc] = __builtin_amdgcn_mfma_f32_16x16x32_bf16(ah[tr], bgl, accg[tr][tc], 0, 0, 0);
                accg[tr][tc] = __builtin_amdgcn_mfma_f32_16x16x32_bf16(al[tr], bgh, accg[tr][tc], 0, 0, 0);
                acch[tr][tc] = __builtin_amdgcn_mfma_f32_16x16x32_bf16(ah[tr], bhh, acch[tr][tc], 0, 0, 0);
                acch[tr][tc] = __builtin_amdgcn_mfma_f32_16x16x32_bf16(ah[tr], bhl, acch[tr][tc], 0, 0, 0);
                acch[tr][tc] = __builtin_amdgcn_mfma_f32_16x16x32_bf16(al[tr], bhh, acch[tr][tc], 0, 0, 0);
            }
        }
    }

    // ---- epilogue: bias + activation, write fp16 ----
#pragma unroll
    for (int tc = 0; tc < 4; ++tc) {
        int e = e0 + wc * 64 + tc * 16 + lr;
        float bgv = bg[e];
        float bhv = bh[e];
#pragma unroll
        for (int tr = 0; tr < 4; ++tr) {
            int mb = m0 + wr * 64 + tr * 16 + kg * 4;
#pragma unroll
            for (int i = 0; i < 4; ++i) {
                float zg = accg[tr][tc][i] + bgv;
                float zh = acch[tr][tc][i] + bhv;
                g_out[(size_t)(mb + i) * E_DIM + e] = (_Float16)fast_sigmoid(zg);
                c_out[(size_t)(mb + i) * E_DIM + e] = (_Float16)fast_tanh(zh);
            }
        }
    }
}

// ---------------- scan pass 1: per-chunk affine composite ----------------
// block 256: 128 d-groups (8 ch each) x 2 chunks. grid (NCH/2, B)
__global__ void chunk_compose(const _Float16* __restrict__ g_arr,
                              const _Float16* __restrict__ c_arr,
                              float* __restrict__ Ac, float* __restrict__ Bc) {
    int tid = threadIdx.x;
    int d8  = tid & 127;                      // which 8-channel group
    int ch  = blockIdx.x * 2 + (tid >> 7);
    int b   = blockIdx.y;
    size_t base = ((size_t)b * 4096 + (size_t)ch * LCH) * 1024 + (size_t)d8 * 8;
    float A[8], Bv[8];
#pragma unroll
    for (int j = 0; j < 8; ++j) { A[j] = 1.f; Bv[j] = 0.f; }
#pragma unroll 8
    for (int t = 0; t < LCH; ++t) {
        h16x8 gv = *(const h16x8*)(g_arr + base + (size_t)t * 1024);
        h16x8 cv = *(const h16x8*)(c_arr + base + (size_t)t * 1024);
#pragma unroll
        for (int j = 0; j < 8; ++j) {
            float g = (float)gv[j];
            float c = (float)cv[j];
            A[j]  = g * A[j];
            Bv[j] = g * Bv[j] + (1.f - g) * c;
        }
    }
    size_t o = ((size_t)b * NCH + ch) * 1024 + (size_t)d8 * 8;
#pragma unroll
    for (int j = 0; j < 2; ++j) {
        *(f32x4*)(Ac + o + j * 4) = (f32x4){A[j*4], A[j*4+1], A[j*4+2], A[j*4+3]};
        *(f32x4*)(Bc + o + j * 4) = (f32x4){Bv[j*4], Bv[j*4+1], Bv[j*4+2], Bv[j*4+3]};
    }
}

// ---------------- scan pass 2: prefix over chunks -> h at chunk entry ----------------
__global__ void chunk_prefix(const float* __restrict__ Ac, const float* __restrict__ Bc,
                             const float* __restrict__ hidden, float* __restrict__ Hst) {
    int d = threadIdx.x;
    int b = blockIdx.x;
    float h = hidden[b * 1024 + d];
#pragma unroll 8
    for (int ch = 0; ch < NCH; ++ch) {
        size_t o = ((size_t)b * NCH + ch) * 1024 + d;
        float A = Ac[o], Bv = Bc[o];
        Hst[o] = h;
        h = A * h + Bv;
    }
}

// ---------------- scan pass 3: apply ----------------
__global__ void chunk_apply(const _Float16* __restrict__ g_arr,
                            const _Float16* __restrict__ c_arr,
                            const float* __restrict__ Hst,
                            float* __restrict__ out) {
    int tid = threadIdx.x;
    int d8  = tid & 127;
    int ch  = blockIdx.x * 2 + (tid >> 7);
    int b   = blockIdx.y;
    size_t base = ((size_t)b * 4096 + (size_t)ch * LCH) * 1024 + (size_t)d8 * 8;
    size_t ho = ((size_t)b * NCH + ch) * 1024 + (size_t)d8 * 8;
    float h[8];
#pragma unroll
    for (int j = 0; j < 2; ++j) {
        f32x4 hv = *(const f32x4*)(Hst + ho + j * 4);
#pragma unroll
        for (int i = 0; i < 4; ++i) h[j * 4 + i] = hv[i];
    }
#pragma unroll 4
    for (int t = 0; t < LCH; ++t) {
        size_t idx = base + (size_t)t * 1024;
        h16x8 gv = *(const h16x8*)(g_arr + idx);
        h16x8 cv = *(const h16x8*)(c_arr + idx);
#pragma unroll
        for (int j = 0; j < 8; ++j) {
            float g = (float)gv[j];
            float c = (float)cv[j];
            h[j] = g * h[j] + (1.f - g) * c;
        }
#pragma unroll
        for (int j = 0; j < 2; ++j)
            *(f32x4*)(out + idx + j * 4) = (f32x4){h[j*4], h[j*4+1], h[j*4+2], h[j*4+3]};
    }
}

extern "C" void kernel_launch(void* const* d_in, const int* in_sizes, int n_in,
                              void* d_out, int out_size, void* d_ws, size_t ws_size,
                              hipStream_t stream) {
    const float* x      = (const float*)d_in[0];
    const float* hidden = (const float*)d_in[1];
    const float* Wg     = (const float*)d_in[2];
    const float* bg     = (const float*)d_in[3];
    const float* Wh     = (const float*)d_in[4];
    const float* bh     = (const float*)d_in[5];
    float* out = (float*)d_out;

    char* ws = (char*)d_ws;
    const size_t WSEG = 2u * 1024u * 1024u;            // 2MB per W half
    u16* wg_hi = (u16*)(ws + 0 * WSEG);
    u16* wg_lo = (u16*)(ws + 1 * WSEG);
    u16* wh_hi = (u16*)(ws + 2 * WSEG);
    u16* wh_lo = (u16*)(ws + 3 * WSEG);
    const size_t HBYTES = (size_t)M_TOTAL * E_DIM * 2; // 64 MiB per fp16 array
    _Float16* g_arr = (_Float16*)(ws + 4 * WSEG);
    _Float16* c_arr = (_Float16*)(ws + 4 * WSEG + HBYTES);
    float* Ac  = (float*)(ws + 4 * WSEG + 2 * HBYTES);
    float* Bc  = (float*)(ws + 4 * WSEG + 2 * HBYTES + WSEG);
    float* Hst = (float*)(ws + 4 * WSEG + 2 * HBYTES + 2 * WSEG);

    // 1) split weights into bf16 hi/lo (grid.y picks Wg/Wh)
    split_w<<<dim3(1024, 2), 256, 0, stream>>>(Wg, Wh, wg_hi, (1024 * 1024) / 4);

    // 2) fused dual GEMM + activation -> fp16 g, c
    gemm_act<<<dim3(M_TOTAL / 128, E_DIM / 128), 256, 0, stream>>>(
        x, wg_hi, wg_lo, wh_hi, wh_lo, bg, bh, g_arr, c_arr);

    // 3) chunked scan
    chunk_compose<<<dim3(NCH / 2, 8), 256, 0, stream>>>(g_arr, c_arr, Ac, Bc);
    chunk_prefix<<<dim3(8), 1024, 0, stream>>>(Ac, Bc, hidden, Hst);
    chunk_apply<<<dim3(NCH / 2, 8), 256, 0, stream>>>(g_arr, c_arr, Hst, out);
}

// Round 3
// 622.631 us; speedup vs baseline: 1.2580x; 1.1222x over previous
//
#include <hip/hip_runtime.h>
#include <hip/hip_bf16.h>
#include <cstdint>

// MinGRU: g=sigmoid(xWg^T+bg), c=tanh(xWh^T+bh), h_t = g*h_{t-1} + (1-g)*c
// B=8, L=4096, D=1024.  M = B*L = 32768, K = E = 1024.
//
// R3 structure:
//  - split-bf16 GEMM on MFMA (x=hi+lo, W=hi+lo, 3 products -> ~fp32 accuracy)
//  - z-merged: one block computes BOTH g and c tiles (x staged once for both)
//  - grid swizzled e-major: consecutive blocks share x m-tile (x HBM-read once)
//  - epilogue via LDS fp32 tile -> coalesced fp16x8 (16B/lane) stores
//  - g,c stored fp16; chunked scan LCH=32, NCH=128, 16 waves/CU
// ws layout: 4 x 2M W splits | g fp16 64MiB | c fp16 64MiB | Ac 4M | Bc 4M | Hst 4M

using u16   = unsigned short;
using f32x4 = __attribute__((ext_vector_type(4))) float;
using s16x8 = __attribute__((ext_vector_type(8))) short;
using u16x4 = __attribute__((ext_vector_type(4))) u16;
using h16x4 = __attribute__((ext_vector_type(4))) _Float16;
using h16x8 = __attribute__((ext_vector_type(8))) _Float16;

#define M_TOTAL 32768
#define K_DIM   1024
#define E_DIM   1024
#define LCH     32     // scan chunk length
#define NCH     128    // chunks per sequence (4096/32)

__device__ inline u16 bf16_rtne(float f) {
    uint32_t u = __float_as_uint(f);
    u += 0x7FFFu + ((u >> 16) & 1u);
    return (u16)(u >> 16);
}

// ---------------- W pre-split: fp32 -> bf16 hi (RTNE) + bf16 lo ----------------
__global__ void split_w(const float* __restrict__ wg, const float* __restrict__ wh,
                        u16* __restrict__ ws_base, int n4) {
    const float* w = blockIdx.y ? wh : wg;
    u16* hi = ws_base + (size_t)blockIdx.y * 2 * 1024 * 1024;  // elements
    u16* lo = hi + 1024 * 1024;
    int i = blockIdx.x * blockDim.x + threadIdx.x;
    if (i >= n4) return;
    f32x4 f = ((const f32x4*)w)[i];
    u16x4 h, l;
#pragma unroll
    for (int c = 0; c < 4; ++c) {
        float fv = f[c];
        u16 hv = bf16_rtne(fv);
        h[c] = hv;
        float fh = __uint_as_float(((uint32_t)hv) << 16);
        l[c] = bf16_rtne(fv - fh);
    }
    ((u16x4*)hi)[i] = h;
    ((u16x4*)lo)[i] = l;
}

__device__ inline float fast_sigmoid(float z) {
    return 1.f / (1.f + __expf(-z));
}
__device__ inline float fast_tanh(float z) {
    return 1.f - 2.f / (__expf(2.f * z) + 1.f);  // saturates correctly
}

// ---------------- GEMM + activation (z-merged, dual accumulators) ----------------
// grid: (E/128, M/128)  [e-major: consecutive blocks share the x m-tile]
__global__ __launch_bounds__(256, 2) void gemm_act(
    const float* __restrict__ x,
    const u16* __restrict__ wg_hi, const u16* __restrict__ wg_lo,
    const u16* __restrict__ wh_hi, const u16* __restrict__ wh_lo,
    const float* __restrict__ bg, const float* __restrict__ bh,
    _Float16* __restrict__ g_out, _Float16* __restrict__ c_out) {

    const int e0 = blockIdx.x * 128;
    const int m0 = blockIdx.y * 128;

    // Staging buffers union'd with the epilogue fp32 tile (epilogue runs after
    // the final sync, so reuse is safe). tile stride 132: rows stay 16B-aligned,
    // row-to-row bank shift 4 -> kg groups land 16 banks apart (<=2-way, free).
    __shared__ __align__(16) union SM {
        struct {
            u16 Ah[128 * 40];   // A-hi, padded stride 40
            u16 Al[128 * 40];   // A-lo
            u16 B[4][128 * 32]; // Wg_hi, Wg_lo, Wh_hi, Wh_lo (unpadded for lds-dma)
        } s;
        float tile[128][132];
    } sm;

    const int tid  = threadIdx.x;
    const int lane = tid & 63;
    const int wave = tid >> 6;
    const int wr = wave >> 1, wc = wave & 1;  // 2x2 wave grid, each 64x64
    const int lr = lane & 15;                 // row/col within 16
    const int kg = lane >> 4;                 // k-group (quad)

    const u16* __restrict__ Wptr[4] = {wg_hi, wg_lo, wh_hi, wh_lo};

    f32x4 accg[4][4], acch[4][4];
#pragma unroll
    for (int tr = 0; tr < 4; ++tr)
#pragma unroll
        for (int tc = 0; tc < 4; ++tc) {
            accg[tr][tc] = (f32x4){0.f, 0.f, 0.f, 0.f};
            acch[tr][tc] = (f32x4){0.f, 0.f, 0.f, 0.f};
        }

    for (int kt = 0; kt < K_DIM / 32; ++kt) {
        __syncthreads();  // previous iter's LDS reads done before overwrite

        // ---- stage B (4 weight regions) via async global->LDS, 16B chunks ----
#pragma unroll
        for (int rgn = 0; rgn < 4; ++rgn) {
#pragma unroll
            for (int j = 0; j < 2; ++j) {
                int ch  = tid + 256 * j;      // 512 chunks of 16B = 8KB
                int row = ch >> 2;            // e-row 0..127
                int kq  = ch & 3;             // 8-elem k group
                size_t goff = (size_t)(e0 + row) * K_DIM + kt * 32 + kq * 8;
                __builtin_amdgcn_global_load_lds(
                    (const __attribute__((address_space(1))) void*)(Wptr[rgn] + goff),
                    (__attribute__((address_space(3))) void*)(&sm.s.B[rgn][ch * 8]), 16, 0, 0);
            }
        }

        // ---- stage A (x rows), convert fp32 -> hi/lo bf16 ----
#pragma unroll
        for (int j = 0; j < 4; ++j) {
            int q   = tid + 256 * j;          // 1024 float4s = 128x32 fp32
            int row = q >> 3;                 // m-row 0..127
            int kq  = q & 7;                  // float4 within row
            f32x4 f = *(const f32x4*)(x + (size_t)(m0 + row) * K_DIM + kt * 32 + kq * 4);
            u16x4 h, l;
#pragma unroll
            for (int c = 0; c < 4; ++c) {
                uint32_t u = __float_as_uint(f[c]);
                h[c] = (u16)(u >> 16);        // truncation split
                float r = f[c] - __uint_as_float(u & 0xFFFF0000u);
                l[c] = bf16_rtne(r);
            }
            *(u16x4*)&sm.s.Ah[row * 40 + kq * 4] = h;
            *(u16x4*)&sm.s.Al[row * 40 + kq * 4] = l;
        }

        __syncthreads();

        // ---- fragments + MFMA (A frags shared across both GEMMs) ----
        s16x8 ah[4], al[4];
#pragma unroll
        for (int tr = 0; tr < 4; ++tr) {
            int r = wr * 64 + tr * 16 + lr;
            ah[tr] = *(const s16x8*)&sm.s.Ah[r * 40 + kg * 8];
            al[tr] = *(const s16x8*)&sm.s.Al[r * 40 + kg * 8];
        }
#pragma unroll
        for (int tc = 0; tc < 4; ++tc) {
            int e = wc * 64 + tc * 16 + lr;
            s16x8 bgh = *(const s16x8*)&sm.s.B[0][e * 32 + kg * 8];
            s16x8 bgl = *(const s16x8*)&sm.s.B[1][e * 32 + kg * 8];
            s16x8 bhh = *(const s16x8*)&sm.s.B[2][e * 32 + kg * 8];
            s16x8 bhl = *(const s16x8*)&sm.s.B[3][e * 32 + kg * 8];
#pragma unroll
            for (int tr = 0; tr < 4; ++tr) {
                accg[tr][tc] = __builtin_amdgcn_mfma_f32_16x16x32_bf16(ah[tr], bgh, accg[tr][tc], 0, 0, 0);
                accg[tr][tc] = __builtin_amdgcn_mfma_f32_16x16x32_bf16(ah[tr], bgl, accg[tr][tc], 0, 0, 0);
                accg[tr][tc] = __builtin_amdgcn_mfma_f32_16x16x32_bf16(al[tr], bgh, accg[tr][tc], 0, 0, 0);
                acch[tr][tc] = __builtin_amdgcn_mfma_f32_16x16x32_bf16(ah[tr], bhh, acch[tr][tc], 0, 0, 0);
                acch[tr][tc] = __builtin_amdgcn_mfma_f32_16x16x32_bf16(ah[tr], bhl, acch[tr][tc], 0, 0, 0);
                acch[tr][tc] = __builtin_amdgcn_mfma_f32_16x16x32_bf16(al[tr], bhh, acch[tr][tc], 0, 0, 0);
            }
        }
    }

    // ---- epilogue: bias+activation -> LDS fp32 tile -> coalesced fp16x8 store ----
#pragma unroll
    for (int arr = 0; arr < 2; ++arr) {
        __syncthreads();  // LDS (staging or previous tile) free for reuse
#pragma unroll
        for (int tc = 0; tc < 4; ++tc) {
            int el = wc * 64 + tc * 16 + lr;
            float bv = (arr ? bh : bg)[e0 + el];
#pragma unroll
            for (int tr = 0; tr < 4; ++tr) {
                int rb = wr * 64 + tr * 16 + kg * 4;
#pragma unroll
                for (int i = 0; i < 4; ++i) {
                    float z = (arr ? acch : accg)[tr][tc][i] + bv;
                    sm.tile[rb + i][el] = arr ? fast_tanh(z) : fast_sigmoid(z);
                }
            }
        }
        __syncthreads();
        _Float16* outp = arr ? c_out : g_out;
#pragma unroll
        for (int p = 0; p < 8; ++p) {
            int row = p * 16 + (tid >> 4);
            int c8  = (tid & 15) * 8;
            f32x4 v0 = *(const f32x4*)&sm.tile[row][c8];
            f32x4 v1 = *(const f32x4*)&sm.tile[row][c8 + 4];
            h16x8 hv;
#pragma unroll
            for (int j = 0; j < 4; ++j) { hv[j] = (_Float16)v0[j]; hv[j + 4] = (_Float16)v1[j]; }
            *(h16x8*)(outp + (size_t)(m0 + row) * E_DIM + e0 + c8) = hv;
        }
    }
}

// ---------------- scan pass 1: per-chunk affine composite ----------------
// grid (NCH, B), 256 threads, 4 channels per thread
__global__ void chunk_compose(const _Float16* __restrict__ g_arr,
                              const _Float16* __restrict__ c_arr,
                              float* __restrict__ Ac, float* __restrict__ Bc) {
    int d4 = threadIdx.x * 4;
    int ch = blockIdx.x;
    int b  = blockIdx.y;
    size_t base = ((size_t)b * 4096 + (size_t)ch * LCH) * 1024 + d4;
    float A[4] = {1.f, 1.f, 1.f, 1.f}, Bv[4] = {0.f, 0.f, 0.f, 0.f};
#pragma unroll 8
    for (int t = 0; t < LCH; ++t) {
        h16x4 gv = *(const h16x4*)(g_arr + base + (size_t)t * 1024);
        h16x4 cv = *(const h16x4*)(c_arr + base + (size_t)t * 1024);
#pragma unroll
        for (int j = 0; j < 4; ++j) {
            float g = (float)gv[j];
            float c = (float)cv[j];
            A[j]  = g * A[j];
            Bv[j] = g * Bv[j] + (1.f - g) * c;
        }
    }
    size_t o = ((size_t)b * NCH + ch) * 1024 + d4;
    *(f32x4*)(Ac + o) = (f32x4){A[0], A[1], A[2], A[3]};
    *(f32x4*)(Bc + o) = (f32x4){Bv[0], Bv[1], Bv[2], Bv[3]};
}

// ---------------- scan pass 2: prefix over chunks -> h at chunk entry ----------------
// 32 blocks x 256 threads = B*D threads; loads pipelined via unroll
__global__ void chunk_prefix(const float* __restrict__ Ac, const float* __restrict__ Bc,
                             const float* __restrict__ hidden, float* __restrict__ Hst) {
    int idx = blockIdx.x * 256 + threadIdx.x;   // 0..8191
    int b = idx >> 10;
    int d = idx & 1023;
    float h = hidden[b * 1024 + d];
#pragma unroll 8
    for (int ch = 0; ch < NCH; ++ch) {
        size_t o = ((size_t)b * NCH + ch) * 1024 + d;
        float A = Ac[o], Bv = Bc[o];
        Hst[o] = h;
        h = A * h + Bv;
    }
}

// ---------------- scan pass 3: apply ----------------
// grid (NCH, B), 256 threads, 4 channels per thread
__global__ void chunk_apply(const _Float16* __restrict__ g_arr,
                            const _Float16* __restrict__ c_arr,
                            const float* __restrict__ Hst,
                            float* __restrict__ out) {
    int d4 = threadIdx.x * 4;
    int ch = blockIdx.x;
    int b  = blockIdx.y;
    size_t base = ((size_t)b * 4096 + (size_t)ch * LCH) * 1024 + d4;
    size_t ho = ((size_t)b * NCH + ch) * 1024 + d4;
    f32x4 hv = *(const f32x4*)(Hst + ho);
    float h[4] = {hv[0], hv[1], hv[2], hv[3]};
#pragma unroll 4
    for (int t = 0; t < LCH; ++t) {
        size_t idx = base + (size_t)t * 1024;
        h16x4 gv = *(const h16x4*)(g_arr + idx);
        h16x4 cv = *(const h16x4*)(c_arr + idx);
#pragma unroll
        for (int j = 0; j < 4; ++j) {
            float g = (float)gv[j];
            float c = (float)cv[j];
            h[j] = g * h[j] + (1.f - g) * c;
        }
        *(f32x4*)(out + idx) = (f32x4){h[0], h[1], h[2], h[3]};
    }
}

extern "C" void kernel_launch(void* const* d_in, const int* in_sizes, int n_in,
                              void* d_out, int out_size, void* d_ws, size_t ws_size,
                              hipStream_t stream) {
    const float* x      = (const float*)d_in[0];
    const float* hidden = (const float*)d_in[1];
    const float* Wg     = (const float*)d_in[2];
    const float* bg     = (const float*)d_in[3];
    const float* Wh     = (const float*)d_in[4];
    const float* bh     = (const float*)d_in[5];
    float* out = (float*)d_out;

    char* ws = (char*)d_ws;
    const size_t WSEG = 2u * 1024u * 1024u;            // 2MB per W half
    u16* wg_hi = (u16*)(ws + 0 * WSEG);
    u16* wg_lo = (u16*)(ws + 1 * WSEG);
    u16* wh_hi = (u16*)(ws + 2 * WSEG);
    u16* wh_lo = (u16*)(ws + 3 * WSEG);
    const size_t HBYTES = (size_t)M_TOTAL * E_DIM * 2; // 64 MiB per fp16 array
    _Float16* g_arr = (_Float16*)(ws + 4 * WSEG);
    _Float16* c_arr = (_Float16*)(ws + 4 * WSEG + HBYTES);
    const size_t SSEG = (size_t)8 * NCH * 1024 * 4;    // 4 MiB per scan array
    float* Ac  = (float*)(ws + 4 * WSEG + 2 * HBYTES);
    float* Bc  = (float*)(ws + 4 * WSEG + 2 * HBYTES + SSEG);
    float* Hst = (float*)(ws + 4 * WSEG + 2 * HBYTES + 2 * SSEG);

    // 1) split weights into bf16 hi/lo (grid.y picks Wg/Wh)
    split_w<<<dim3(1024, 2), 256, 0, stream>>>(Wg, Wh, wg_hi, (1024 * 1024) / 4);

    // 2) fused dual GEMM + activation -> fp16 g, c  (e-major grid)
    gemm_act<<<dim3(E_DIM / 128, M_TOTAL / 128), 256, 0, stream>>>(
        x, wg_hi, wg_lo, wh_hi, wh_lo, bg, bh, g_arr, c_arr);

    // 3) chunked scan
    chunk_compose<<<dim3(NCH, 8), 256, 0, stream>>>(g_arr, c_arr, Ac, Bc);
    chunk_prefix<<<dim3(32), 256, 0, stream>>>(Ac, Bc, hidden, Hst);
    chunk_apply<<<dim3(NCH, 8), 256, 0, stream>>>(g_arr, c_arr, Hst, out);
}